// Round 1
// baseline (331.047 us; speedup 1.0000x reference)
//
#include <hip/hip_runtime.h>

#define DF 256
#define HID 16

// Tiny precompute: w[k] = sum_j W[k,j] * W_fc[j];  c = b_conv . W_fc + b_fc
__global__ void prep_kernel(const float* __restrict__ W, const float* __restrict__ b_conv,
                            const float* __restrict__ W_fc, const float* __restrict__ b_fc,
                            float* __restrict__ wvec, float* __restrict__ cterm) {
    int k = threadIdx.x;  // 256 threads
    float acc = 0.f;
#pragma unroll
    for (int j = 0; j < HID; ++j) acc += W[k * HID + j] * W_fc[j];
    wvec[k] = acc;
    if (k == 0) {
        float c = 0.f;
#pragma unroll
        for (int j = 0; j < HID; ++j) c += b_conv[j] * W_fc[j];
        cterm[0] = c + b_fc[0];
    }
}

// deg count: one int atomic per edge target
__global__ void count_kernel(const int* __restrict__ dst, unsigned* __restrict__ cnt, int E) {
    int stride = gridDim.x * blockDim.x;
    for (int e = blockIdx.x * blockDim.x + threadIdx.x; e < E; e += stride)
        atomicAdd(&cnt[dst[e]], 1u);
}

// Per-node: s[i] = x[i].w (64-lane wave dot), dinv[i] = rsqrt(deg), out init = self-loop + bias
__global__ void node_kernel(const float* __restrict__ x, const unsigned* __restrict__ cnt,
                            const float* __restrict__ wvec, const float* __restrict__ cterm,
                            float* __restrict__ dinv, float* __restrict__ sval,
                            float* __restrict__ out, int N) {
    int lane = threadIdx.x & 63;
    int row = blockIdx.x * 4 + (threadIdx.x >> 6);
    if (row >= N) return;
    float4 wv = reinterpret_cast<const float4*>(wvec)[lane];
    float4 xv = reinterpret_cast<const float4*>(x + (size_t)row * DF)[lane];
    float acc = xv.x * wv.x + xv.y * wv.y + xv.z * wv.z + xv.w * wv.w;
#pragma unroll
    for (int off = 32; off > 0; off >>= 1) acc += __shfl_xor(acc, off, 64);
    if (lane == 0) {
        float deg = 1.0f + (float)cnt[row];
        dinv[row] = rsqrtf(deg);
        sval[row] = acc;
        out[row] = acc / deg + cterm[0];  // self-loop term + fused bias
    }
}

// Edge scatter: out[dst] += dinv[src]*dinv[dst]*s[src]  (gathers are L2-resident, 400KB arrays)
__global__ void scatter_kernel(const int* __restrict__ src, const int* __restrict__ dst,
                               const float* __restrict__ dinv, const float* __restrict__ sval,
                               float* __restrict__ out, int E) {
    int stride = gridDim.x * blockDim.x;
    for (int e = blockIdx.x * blockDim.x + threadIdx.x; e < E; e += stride) {
        int si = src[e];
        int di = dst[e];
        atomicAdd(&out[di], dinv[si] * dinv[di] * sval[si]);
    }
}

extern "C" void kernel_launch(void* const* d_in, const int* in_sizes, int n_in,
                              void* d_out, int out_size, void* d_ws, size_t ws_size,
                              hipStream_t stream) {
    const float* x      = (const float*)d_in[0];
    const int*   ei     = (const int*)d_in[1];
    const float* W      = (const float*)d_in[2];
    const float* b_conv = (const float*)d_in[3];
    const float* W_fc   = (const float*)d_in[4];
    const float* b_fc   = (const float*)d_in[5];
    float* out = (float*)d_out;

    const int N = in_sizes[0] / DF;   // 100000
    const int E = in_sizes[1] / 2;    // 3200000
    const int* src = ei;              // edge_index[0]
    const int* dst = ei + E;          // edge_index[1]

    char* ws = (char*)d_ws;
    float*    wvec  = (float*)ws;                   // 256 f32
    float*    cterm = wvec + 256;                   // 1 f32 (pad to 512)
    unsigned* cnt   = (unsigned*)(ws + 512 * 4);    // N u32
    float*    dinv  = (float*)(cnt + N);            // N f32
    float*    sval  = dinv + N;                     // N f32

    hipMemsetAsync(cnt, 0, (size_t)N * sizeof(unsigned), stream);
    prep_kernel<<<1, 256, 0, stream>>>(W, b_conv, W_fc, b_fc, wvec, cterm);
    count_kernel<<<2048, 256, 0, stream>>>(dst, cnt, E);
    node_kernel<<<(N + 3) / 4, 256, 0, stream>>>(x, cnt, wvec, cterm, dinv, sval, out, N);
    scatter_kernel<<<2048, 256, 0, stream>>>(src, dst, dinv, sval, out, E);
}